// Round 1
// baseline (134.116 us; speedup 1.0000x reference)
//
#include <hip/hip_runtime.h>
#include <math.h>

#define NB   16384
#define SEQ  10
#define DIM  8
#define TRIL 36

__device__ __forceinline__ constexpr int tri(int r, int c) { return r * (r + 1) / 2 + c; } // r >= c

// Build one density matrix (lower-sym storage, 36 doubles) from a 36-float
// embedding row and either accumulate into dst (ACCUM) or overwrite it.
// density = (L L^T + 2e-6 I) / (tr(L L^T) + 1.6e-5 + 1e-6), diag(L) clamped >= 1e-4.
template <bool ACCUM>
__device__ __forceinline__ void add_density(const float* __restrict__ p, double (&dst)[TRIL]) {
    double L[TRIL];
    #pragma unroll
    for (int i = 0; i < TRIL; ++i) L[i] = (double)p[i];
    #pragma unroll
    for (int d = 0; d < DIM; ++d) L[tri(d, d)] = fmax(L[tri(d, d)], 1.0e-4);

    // tr(L L^T) = ||L||_F^2 over the stored tril entries; +8*2e-6 from the added diag
    double tr = 1.6e-5;
    #pragma unroll
    for (int i = 0; i < TRIL; ++i) tr += L[i] * L[i];
    double inv = 1.0 / (tr + 1.0e-6);

    #pragma unroll
    for (int i = 0; i < DIM; ++i) {
        #pragma unroll
        for (int j = 0; j <= i; ++j) {
            double sum = (i == j) ? 2.0e-6 : 0.0;
            #pragma unroll
            for (int k = 0; k <= j; ++k) sum += L[tri(i, k)] * L[tri(j, k)];
            if (ACCUM) dst[tri(i, j)] += sum * inv;
            else       dst[tri(i, j)]  = sum * inv;
        }
    }
}

__global__ void __launch_bounds__(64)
qcbow_kernel(const int* __restrict__ contexts,  // [NB, SEQ]
             const int* __restrict__ targets,   // [NB]
             const float* __restrict__ emb,     // [100000, TRIL]
             float* __restrict__ out)           // [NB]
{
    int b = blockIdx.x * 64 + threadIdx.x;
    if (b >= NB) return;

    // ---- masked average of context densities ----
    double A[TRIL];
    #pragma unroll
    for (int i = 0; i < TRIL; ++i) A[i] = 0.0;
    double cnt = 0.0;

    for (int s = 0; s < SEQ; ++s) {
        int tok = contexts[b * SEQ + s];
        if (tok != 0) {
            add_density<true>(emb + (size_t)tok * TRIL, A);
            cnt += 1.0;
        }
    }
    double invc = 1.0 / cnt;
    #pragma unroll
    for (int i = 0; i < TRIL; ++i) A[i] *= invc;
    // A <- rho_ctx + 1e-6 I  (this is sqrt_rho^2 exactly; see _matrix_sqrt eps)
    #pragma unroll
    for (int d = 0; d < DIM; ++d) A[tri(d, d)] += 1.0e-6;

    // ---- target density ----
    double sig[TRIL];
    add_density<false>(emb + (size_t)targets[b] * TRIL, sig);

    // ---- Cholesky A = Lc Lc^T in place (lower-sym storage) ----
    #pragma unroll
    for (int j = 0; j < DIM; ++j) {
        double d = A[tri(j, j)];
        #pragma unroll
        for (int k = 0; k < j; ++k) d -= A[tri(j, k)] * A[tri(j, k)];
        d = sqrt(fmax(d, 1.0e-30));
        A[tri(j, j)] = d;
        double invd = 1.0 / d;
        #pragma unroll
        for (int i = j + 1; i < DIM; ++i) {
            double v = A[tri(i, j)];
            #pragma unroll
            for (int k = 0; k < j; ++k) v -= A[tri(i, k)] * A[tri(j, k)];
            A[tri(i, j)] = v * invd;
        }
    }

    // ---- C = Lc^T * sig * Lc : symmetric, eigenvalues == eig((rho+eps I) sigma)
    double C[TRIL];
    #pragma unroll
    for (int j = 0; j < DIM; ++j) {
        double w[DIM];
        #pragma unroll
        for (int k = 0; k < DIM; ++k) {
            double sum = 0.0;
            #pragma unroll
            for (int l = j; l < DIM; ++l) {
                double sk = (k >= l) ? sig[tri(k, l)] : sig[tri(l, k)];
                sum += sk * A[tri(l, j)];
            }
            w[k] = sum;
        }
        #pragma unroll
        for (int i = 0; i <= j; ++i) {
            double sum = 0.0;
            #pragma unroll
            for (int k = i; k < DIM; ++k) sum += A[tri(k, i)] * w[k];
            C[tri(j, i)] = sum;  // store at (row=j, col=i), i <= j
        }
    }

    // ---- cyclic Jacobi, eigenvalues only (8 sweeps, quadratic convergence) ----
    for (int sweep = 0; sweep < 8; ++sweep) {
        #pragma unroll
        for (int p = 0; p < DIM - 1; ++p) {
            #pragma unroll
            for (int q = p + 1; q < DIM; ++q) {
                double apq = C[tri(q, p)];
                if (fabs(apq) > 1.0e-300) {
                    double app = C[tri(p, p)];
                    double aqq = C[tri(q, q)];
                    double tau = (aqq - app) / (2.0 * apq);
                    double t = 1.0 / (fabs(tau) + sqrt(1.0 + tau * tau));
                    t = (tau >= 0.0) ? t : -t;
                    double c = 1.0 / sqrt(1.0 + t * t);
                    double s = t * c;
                    C[tri(p, p)] = app - t * apq;
                    C[tri(q, q)] = aqq + t * apq;
                    C[tri(q, p)] = 0.0;
                    #pragma unroll
                    for (int k = 0; k < DIM; ++k) {
                        if (k == p || k == q) continue;
                        const int ikp = (k > p) ? tri(k, p) : tri(p, k);
                        const int ikq = (k > q) ? tri(k, q) : tri(q, k);
                        double akp = C[ikp];
                        double akq = C[ikq];
                        C[ikp] = c * akp - s * akq;
                        C[ikq] = s * akp + c * akq;
                    }
                }
            }
        }
    }

    // ---- fidelity: f = sum sqrt(|lambda| + 1e-6), clip, -log ----
    double f = 0.0;
    #pragma unroll
    for (int d = 0; d < DIM; ++d) f += sqrt(fabs(C[tri(d, d)]) + 1.0e-6);
    f = fmin(f, 1.0);
    f = fmax(f, 1.0e-8);
    out[b] = (float)(-log(f));
}

extern "C" void kernel_launch(void* const* d_in, const int* in_sizes, int n_in,
                              void* d_out, int out_size, void* d_ws, size_t ws_size,
                              hipStream_t stream) {
    const int*   contexts = (const int*)d_in[0];
    const int*   targets  = (const int*)d_in[1];
    const float* emb      = (const float*)d_in[2];
    float*       out      = (float*)d_out;

    qcbow_kernel<<<dim3(NB / 64), dim3(64), 0, stream>>>(contexts, targets, emb, out);
}

// Round 2
// 99.728 us; speedup vs baseline: 1.3448x; 1.3448x over previous
//
#include <hip/hip_runtime.h>
#include <math.h>

#define NB   16384
#define SEQ  10
#define DIM  8
#define TRIL 36

__device__ __forceinline__ constexpr int tri(int r, int c) { return r * (r + 1) / 2 + c; } // r >= c

// fp64 rsqrt: v_rsq_f64 seed (~1e-7 rel) + 2 Newton -> ~1e-16 rel. No fp64 div/sqrt chains.
__device__ __forceinline__ double fast_rsqrt(double x) {
    double r = __builtin_amdgcn_rsq(x);
    r = r * (1.5 - 0.5 * x * r * r);
    r = r * (1.5 - 0.5 * x * r * r);
    return r;
}
// fp64 reciprocal: v_rcp_f64 seed + 2 Newton.
__device__ __forceinline__ double fast_rcp(double x) {
    double r = __builtin_amdgcn_rcp(x);
    r = r * (2.0 - x * r);
    r = r * (2.0 - x * r);
    return r;
}
__device__ __forceinline__ double fast_sqrt(double x) { return x * fast_rsqrt(x); }

// Build one density matrix (lower-sym storage, 36 doubles) from a 36-float
// embedding row; accumulate (ACCUM) or overwrite.
// density = (L L^T + 2e-6 I) / (tr(L L^T) + 1.6e-5 + 1e-6), diag(L) clamped >= 1e-4.
template <bool ACCUM>
__device__ __forceinline__ void add_density(const float* __restrict__ p, double (&dst)[TRIL]) {
    double L[TRIL];
    #pragma unroll
    for (int i = 0; i < TRIL; ++i) L[i] = (double)p[i];
    #pragma unroll
    for (int d = 0; d < DIM; ++d) L[tri(d, d)] = fmax(L[tri(d, d)], 1.0e-4);

    double tr = 1.6e-5;
    #pragma unroll
    for (int i = 0; i < TRIL; ++i) tr += L[i] * L[i];
    double inv = fast_rcp(tr + 1.0e-6);

    #pragma unroll
    for (int i = 0; i < DIM; ++i) {
        #pragma unroll
        for (int j = 0; j <= i; ++j) {
            double sum = (i == j) ? 2.0e-6 : 0.0;
            #pragma unroll
            for (int k = 0; k <= j; ++k) sum += L[tri(i, k)] * L[tri(j, k)];
            if (ACCUM) dst[tri(i, j)] += sum * inv;
            else       dst[tri(i, j)]  = sum * inv;
        }
    }
}

__global__ void __launch_bounds__(64)
qcbow_kernel(const int* __restrict__ contexts,  // [NB, SEQ]
             const int* __restrict__ targets,   // [NB]
             const float* __restrict__ emb,     // [100000, TRIL]
             float* __restrict__ out)           // [NB]
{
    int b = blockIdx.x * 64 + threadIdx.x;

    // ---- masked average of context densities ----
    double A[TRIL];
    #pragma unroll
    for (int i = 0; i < TRIL; ++i) A[i] = 0.0;
    double cnt = 0.0;

    for (int s = 0; s < SEQ; ++s) {
        int tok = contexts[b * SEQ + s];
        if (tok != 0) {
            add_density<true>(emb + (size_t)tok * TRIL, A);
            cnt += 1.0;
        }
    }
    double invc = fast_rcp(cnt);
    #pragma unroll
    for (int i = 0; i < TRIL; ++i) A[i] *= invc;
    // A <- rho_ctx + 1e-6 I  (== sqrt_rho^2 exactly, per _matrix_sqrt eps)
    #pragma unroll
    for (int d = 0; d < DIM; ++d) A[tri(d, d)] += 1.0e-6;

    // ---- target density ----
    double sig[TRIL];
    add_density<false>(emb + (size_t)targets[b] * TRIL, sig);

    // ---- Cholesky A = Lc Lc^T in place (no fp64 div/sqrt: rsqrt+Newton) ----
    #pragma unroll
    for (int j = 0; j < DIM; ++j) {
        double d = A[tri(j, j)];
        #pragma unroll
        for (int k = 0; k < j; ++k) d -= A[tri(j, k)] * A[tri(j, k)];
        d = fmax(d, 1.0e-30);
        double invd = fast_rsqrt(d);
        A[tri(j, j)] = d * invd;   // sqrt(d)
        #pragma unroll
        for (int i = j + 1; i < DIM; ++i) {
            double v = A[tri(i, j)];
            #pragma unroll
            for (int k = 0; k < j; ++k) v -= A[tri(i, k)] * A[tri(j, k)];
            A[tri(i, j)] = v * invd;
        }
    }

    // ---- C = Lc^T * sig * Lc : symmetric; eig(C) == eig((rho+eps I) sigma) ----
    double C[TRIL];
    #pragma unroll
    for (int j = 0; j < DIM; ++j) {
        double w[DIM];
        #pragma unroll
        for (int k = 0; k < DIM; ++k) {
            double sum = 0.0;
            #pragma unroll
            for (int l = j; l < DIM; ++l) {
                double sk = (k >= l) ? sig[tri(k, l)] : sig[tri(l, k)];
                sum += sk * A[tri(l, j)];
            }
            w[k] = sum;
        }
        #pragma unroll
        for (int i = 0; i <= j; ++i) {
            double sum = 0.0;
            #pragma unroll
            for (int k = i; k < DIM; ++k) sum += A[tri(k, i)] * w[k];
            C[tri(j, i)] = sum;  // (row=j, col=i), i <= j
        }
    }

    // ---- cyclic Jacobi, eigenvalues only.
    // Angles in fp32 (cheap v_rcp_f32/v_sqrt_f32); rotation applied in fp64 with
    // c^2+s^2 = 1 to ~1e-14 (one fp64 Newton on c) => true similarity, eigenvalue
    // error is relative-only. Full-form 2x2 update (t-shortcut is NOT a similarity
    // for inexact angles). Early-exit when off-diag Frobenius^2 < 1e-14.
    for (int sweep = 0; sweep < 8; ++sweep) {
        #pragma unroll
        for (int p = 0; p < DIM - 1; ++p) {
            #pragma unroll
            for (int q = p + 1; q < DIM; ++q) {
                double apq = C[tri(q, p)];
                if (fabs(apq) > 1.0e-20) {   // below this: zero-effect, and fp32 would inf/NaN
                    double app = C[tri(p, p)];
                    double aqq = C[tri(q, q)];
                    // fp32 angle
                    float tauf = ((float)aqq - (float)app) * (0.5f * __builtin_amdgcn_rcpf((float)apq));
                    float tf = __builtin_amdgcn_rcpf(fabsf(tauf) + sqrtf(1.0f + tauf * tauf));
                    tf = (tauf >= 0.0f) ? tf : -tf;
                    double t = (double)tf;
                    double x = 1.0 + t * t;
                    double c = (double)__builtin_amdgcn_rsqf((float)x);
                    c = c * (1.5 - 0.5 * x * c * c);   // fp64 Newton: c = 1/sqrt(1+t^2) to ~1e-14
                    double s = t * c;
                    double cc = c * c, ss = s * s, cs = c * s;
                    C[tri(p, p)] = cc * app + ss * aqq - 2.0 * cs * apq;
                    C[tri(q, q)] = ss * app + cc * aqq + 2.0 * cs * apq;
                    C[tri(q, p)] = cs * (app - aqq) + (cc - ss) * apq;  // ~1e-7*apq residual
                    #pragma unroll
                    for (int k = 0; k < DIM; ++k) {
                        if (k == p || k == q) continue;
                        const int ikp = (k > p) ? tri(k, p) : tri(p, k);
                        const int ikq = (k > q) ? tri(k, q) : tri(q, k);
                        double akp = C[ikp];
                        double akq = C[ikq];
                        C[ikp] = c * akp - s * akq;
                        C[ikq] = s * akp + c * akq;
                    }
                }
            }
        }
        if (sweep >= 2) {
            double off2 = 0.0;
            #pragma unroll
            for (int i = 1; i < DIM; ++i) {
                #pragma unroll
                for (int j = 0; j < i; ++j) off2 += C[tri(i, j)] * C[tri(i, j)];
            }
            if (__all(off2 < 1.0e-14)) break;   // wave-uniform exit
        }
    }

    // ---- fidelity: f = sum sqrt(|lambda| + 1e-6), clip, -log ----
    double f = 0.0;
    #pragma unroll
    for (int d = 0; d < DIM; ++d) f += fast_sqrt(fabs(C[tri(d, d)]) + 1.0e-6);
    f = fmin(f, 1.0);
    f = fmax(f, 1.0e-8);
    out[b] = (float)(-log(f));
}

extern "C" void kernel_launch(void* const* d_in, const int* in_sizes, int n_in,
                              void* d_out, int out_size, void* d_ws, size_t ws_size,
                              hipStream_t stream) {
    const int*   contexts = (const int*)d_in[0];
    const int*   targets  = (const int*)d_in[1];
    const float* emb      = (const float*)d_in[2];
    float*       out      = (float*)d_out;

    qcbow_kernel<<<dim3(NB / 64), dim3(64), 0, stream>>>(contexts, targets, emb, out);
}

// Round 3
// 94.977 us; speedup vs baseline: 1.4121x; 1.0500x over previous
//
#include <hip/hip_runtime.h>
#include <math.h>

#define NB   16384
#define SEQ  10
#define DIM  8
#define TRIL 36

__device__ __forceinline__ constexpr int tri(int r, int c) { return r * (r + 1) / 2 + c; } // r >= c

// fp64 rsqrt/rcp via HW seed + Newton (no fp64 div/sqrt chains)
__device__ __forceinline__ double fast_rsqrt(double x) {
    double r = __builtin_amdgcn_rsq(x);
    r = r * (1.5 - 0.5 * x * r * r);
    r = r * (1.5 - 0.5 * x * r * r);
    return r;
}
__device__ __forceinline__ double fast_rcp(double x) {
    double r = __builtin_amdgcn_rcp(x);
    r = r * (2.0 - x * r);
    r = r * (2.0 - x * r);
    return r;
}
__device__ __forceinline__ double fast_sqrt(double x) { return x * fast_rsqrt(x); }

// density = (L L^T + 2e-6 I) / (||L||_F^2 + 1.6e-5 + 1e-6), diag(L) clamped >= 1e-4 (in fp32,
// matching the reference's fp32 clip). L kept in fp32 regs (exact inputs); products in fp64.
// emb rows are 144 B = 9 float4, 16B-aligned (144 = 9*16) -> vector loads.
template <bool ACCUM>
__device__ __forceinline__ void add_density(const float* __restrict__ p, double (&dst)[TRIL]) {
    float Lf[TRIL];
    const float4* p4 = (const float4*)p;
    #pragma unroll
    for (int i = 0; i < 9; ++i) {
        float4 v = p4[i];
        Lf[4*i+0] = v.x; Lf[4*i+1] = v.y; Lf[4*i+2] = v.z; Lf[4*i+3] = v.w;
    }
    #pragma unroll
    for (int d = 0; d < DIM; ++d) Lf[tri(d, d)] = fmaxf(Lf[tri(d, d)], 1.0e-4f);

    double tr = 1.6e-5;
    #pragma unroll
    for (int i = 0; i < TRIL; ++i) { double v = (double)Lf[i]; tr += v * v; }
    double inv = fast_rcp(tr + 1.0e-6);

    #pragma unroll
    for (int i = 0; i < DIM; ++i) {
        #pragma unroll
        for (int j = 0; j <= i; ++j) {
            double sum = (i == j) ? 2.0e-6 : 0.0;
            #pragma unroll
            for (int k = 0; k <= j; ++k) sum += (double)Lf[tri(i, k)] * (double)Lf[tri(j, k)];
            if (ACCUM) dst[tri(i, j)] += sum * inv;
            else       dst[tri(i, j)]  = sum * inv;
        }
    }
}

// in-place Cholesky of sym-36 (lower) fp64
__device__ __forceinline__ void chol36(double (&M)[TRIL]) {
    #pragma unroll
    for (int j = 0; j < DIM; ++j) {
        double d = M[tri(j, j)];
        #pragma unroll
        for (int k = 0; k < j; ++k) d -= M[tri(j, k)] * M[tri(j, k)];
        d = fmax(d, 1.0e-30);
        double invd = fast_rsqrt(d);
        M[tri(j, j)] = d * invd;
        #pragma unroll
        for (int i = j + 1; i < DIM; ++i) {
            double v = M[tri(i, j)];
            #pragma unroll
            for (int k = 0; k < j; ++k) v -= M[tri(i, k)] * M[tri(j, k)];
            M[tri(i, j)] = v * invd;
        }
    }
}

// 4 lanes cooperate per batch element. Lane g owns G columns (2g, 2g+1).
__global__ void __launch_bounds__(64)
qcbow_kernel(const int* __restrict__ contexts,  // [NB, SEQ]
             const int* __restrict__ targets,   // [NB]
             const float* __restrict__ emb,     // [100000, TRIL]
             float* __restrict__ out)           // [NB]
{
    const int tid = blockIdx.x * 64 + threadIdx.x;
    const int b = tid >> 2;
    const int g = threadIdx.x & 3;

    // ---- phase 1: partial context density (tokens g, g+4, g+8) ----
    double A[TRIL];
    #pragma unroll
    for (int i = 0; i < TRIL; ++i) A[i] = 0.0;
    double cnt = 0.0;
    for (int s = g; s < SEQ; s += 4) {
        int tok = contexts[b * SEQ + s];
        if (tok != 0) {
            add_density<true>(emb + (size_t)tok * TRIL, A);
            cnt += 1.0;
        }
    }

    // ---- sigma (target density), redundant on all 4 lanes (same cacheline) ----
    double W[TRIL];
    add_density<false>(emb + (size_t)targets[b] * TRIL, W);

    // ---- allreduce A,cnt over the 4-lane group (DS ops; overlaps chol(W) VALU) ----
    #pragma unroll
    for (int i = 0; i < TRIL; ++i) A[i] += __shfl_xor(A[i], 1, 4);
    cnt += __shfl_xor(cnt, 1, 4);
    #pragma unroll
    for (int i = 0; i < TRIL; ++i) A[i] += __shfl_xor(A[i], 2, 4);
    cnt += __shfl_xor(cnt, 2, 4);

    // W <- chol(sigma)  (sigma min-eig >= 2e-6/tr > 0)
    chol36(W);

    // ---- A <- rho_ctx + 1e-6 I, then A <- Lc = chol(A) ----
    double invc = fast_rcp(cnt);
    #pragma unroll
    for (int i = 0; i < TRIL; ++i) A[i] *= invc;
    #pragma unroll
    for (int d = 0; d < DIM; ++d) A[tri(d, d)] += 1.0e-6;
    chol36(A);

    // ---- G = Lc^T * W; lane g holds columns ja=2g, jb=2g+1.
    // eig((rho+eps I) sigma) = eig(Lc^T sigma Lc) = eig(G G^T) = sing(G)^2.
    // W-column pick: static 4-way switch (no runtime register indexing).
    double wa[DIM], wb[DIM];
#define PICKW(JA, JB)                                                              \
    {                                                                              \
        _Pragma("unroll")                                                          \
        for (int k = 0; k < DIM; ++k) wa[k] = (k >= (JA)) ? W[tri(k, (JA))] : 0.0; \
        _Pragma("unroll")                                                          \
        for (int k = 0; k < DIM; ++k) wb[k] = (k >= (JB)) ? W[tri(k, (JB))] : 0.0; \
    }
    switch (g) {
        case 0: PICKW(0, 1); break;
        case 1: PICKW(2, 3); break;
        case 2: PICKW(4, 5); break;
        default: PICKW(6, 7); break;
    }
#undef PICKW

    double a[DIM], bc[DIM];   // my two G columns (indexed by row k)
    #pragma unroll
    for (int i = 0; i < DIM; ++i) {
        double sa = 0.0, sb = 0.0;
        #pragma unroll
        for (int k = i; k < DIM; ++k) {
            double lk = A[tri(k, i)];      // (Lc^T)[i][k]
            sa += lk * wa[k];
            sb += lk * wb[k];
        }
        a[i] = sa; bc[i] = sb;
    }

    // ---- systolic one-sided Jacobi (Brent-Luk): each round the resident pair is
    // lane-local; exchange pattern (slot cycle 1->2->4->6->7->5->3->1, slot0 fixed)
    // covers all 28 pairs in 7 rounds and is identical every round.
    for (int sweep = 0; sweep < 10; ++sweep) {
        double maxz2 = 0.0;
        #pragma unroll
        for (int r = 0; r < 7; ++r) {
            double x = 0.0, y = 0.0, z = 0.0;
            #pragma unroll
            for (int k = 0; k < DIM; ++k) {
                x += a[k] * a[k];
                y += bc[k] * bc[k];
                z += a[k] * bc[k];
            }
            double z2 = z * z;
            maxz2 = fmax(maxz2, z2);
            if (z2 > 1.0e-20) {
                // fp32 angle seed; c tightened by one fp64 Newton -> c^2+s^2 = 1 + O(1e-14)
                float tauf = (float)(y - x) * (0.5f * __builtin_amdgcn_rcpf((float)z));
                float tf = __builtin_amdgcn_rcpf(fabsf(tauf) + sqrtf(1.0f + tauf * tauf));
                tf = (tauf >= 0.0f) ? tf : -tf;
                double t = (double)tf;
                double x2 = 1.0 + t * t;
                double c = (double)__builtin_amdgcn_rsqf((float)x2);
                c = c * (1.5 - 0.5 * x2 * c * c);
                double s = t * c;
                #pragma unroll
                for (int k = 0; k < DIM; ++k) {
                    double na = c * a[k] - s * bc[k];
                    double nb = s * a[k] + c * bc[k];
                    a[k] = na; bc[k] = nb;
                }
            }
            // exchange (uniform, outside the divergent rotate branch):
            //   new_a[g] = (g==0) ? a : from lane g-1 (its b if lane0, else its a)
            //   new_b[g] = (g==3) ? my old a : b from lane g+1
            #pragma unroll
            for (int k = 0; k < DIM; ++k) {
                double olda = a[k];
                double sa = (g == 0) ? bc[k] : a[k];
                double ta = __shfl(sa, (g + 3) & 3, 4);
                double tb = __shfl(bc[k], (g + 1) & 3, 4);
                a[k]  = (g == 0) ? olda : ta;
                bc[k] = (g == 3) ? olda : tb;
            }
        }
        if (sweep >= 2 && __all(maxz2 < 1.0e-18)) break;
    }

    // ---- fidelity: lambda_i = ||col_i||^2; f = sum sqrt(lambda + 1e-6) ----
    double x = 0.0, y = 0.0;
    #pragma unroll
    for (int k = 0; k < DIM; ++k) { x += a[k] * a[k]; y += bc[k] * bc[k]; }
    double fp = fast_sqrt(x + 1.0e-6) + fast_sqrt(y + 1.0e-6);
    fp += __shfl_xor(fp, 1, 4);
    fp += __shfl_xor(fp, 2, 4);
    if (g == 0) {
        double f = fmin(fp, 1.0);
        f = fmax(f, 1.0e-8);
        out[b] = (float)(-log(f));
    }
}

extern "C" void kernel_launch(void* const* d_in, const int* in_sizes, int n_in,
                              void* d_out, int out_size, void* d_ws, size_t ws_size,
                              hipStream_t stream) {
    const int*   contexts = (const int*)d_in[0];
    const int*   targets  = (const int*)d_in[1];
    const float* emb      = (const float*)d_in[2];
    float*       out      = (float*)d_out;

    qcbow_kernel<<<dim3(NB * 4 / 64), dim3(64), 0, stream>>>(contexts, targets, emb, out);
}

// Round 4
// 85.807 us; speedup vs baseline: 1.5630x; 1.1069x over previous
//
#include <hip/hip_runtime.h>
#include <math.h>

#define NB   16384
#define SEQ  10
#define DIM  8
#define TRIL 36

__device__ __forceinline__ constexpr int tri(int r, int c) { return r * (r + 1) / 2 + c; } // r >= c

// ---- DPP quad-perm helpers (VALU cross-lane within each aligned quad) ----
// ctrl byte = s0 | s1<<2 | s2<<4 | s3<<6 : lane i reads from quad-lane s_i.
template <int CTRL>
__device__ __forceinline__ float fperm(float v) {
    return __int_as_float(__builtin_amdgcn_mov_dpp(__float_as_int(v), CTRL, 0xf, 0xf, true));
}
template <int CTRL>
__device__ __forceinline__ double dperm(double v) {
    long long u = __double_as_longlong(v);
    int lo = (int)(u & 0xffffffffLL);
    int hi = (int)(u >> 32);
    lo = __builtin_amdgcn_mov_dpp(lo, CTRL, 0xf, 0xf, true);
    hi = __builtin_amdgcn_mov_dpp(hi, CTRL, 0xf, 0xf, true);
    return __longlong_as_double(((long long)hi << 32) | (long long)(unsigned)lo);
}
// quad perms: XOR1=[1,0,3,2]=0xB1, XOR2=[2,3,0,1]=0x4E,
// RECV_A: from (g+3)&3 = [3,0,1,2] = 0x93 ; RECV_B: from (g+1)&3 = [1,2,3,0] = 0x39.

// fp64 rsqrt/rcp via HW seed + Newton (no fp64 div/sqrt chains)
__device__ __forceinline__ double fast_rsqrt(double x) {
    double r = __builtin_amdgcn_rsq(x);
    r = r * (1.5 - 0.5 * x * r * r);
    r = r * (1.5 - 0.5 * x * r * r);
    return r;
}
__device__ __forceinline__ double fast_rcp(double x) {
    double r = __builtin_amdgcn_rcp(x);
    r = r * (2.0 - x * r);
    r = r * (2.0 - x * r);
    return r;
}
__device__ __forceinline__ double fast_sqrt(double x) { return x * fast_rsqrt(x); }

// density = (L L^T + 2e-6 I) / (||L||_F^2 + 1.6e-5 + 1e-6), diag(L) clamped >= 1e-4.
// Inputs exact fp32; all products/sums fp64 (density errors perturb eigenvalues ABSOLUTELY,
// so this stage must stay accurate). emb rows are 144 B = 9 aligned float4.
template <bool ACCUM>
__device__ __forceinline__ void add_density(const float* __restrict__ p, double (&dst)[TRIL]) {
    float Lf[TRIL];
    const float4* p4 = (const float4*)p;
    #pragma unroll
    for (int i = 0; i < 9; ++i) {
        float4 v = p4[i];
        Lf[4*i+0] = v.x; Lf[4*i+1] = v.y; Lf[4*i+2] = v.z; Lf[4*i+3] = v.w;
    }
    #pragma unroll
    for (int d = 0; d < DIM; ++d) Lf[tri(d, d)] = fmaxf(Lf[tri(d, d)], 1.0e-4f);

    double tr = 1.6e-5;
    #pragma unroll
    for (int i = 0; i < TRIL; ++i) { double v = (double)Lf[i]; tr += v * v; }
    double inv = fast_rcp(tr + 1.0e-6);

    #pragma unroll
    for (int i = 0; i < DIM; ++i) {
        #pragma unroll
        for (int j = 0; j <= i; ++j) {
            double sum = (i == j) ? 2.0e-6 : 0.0;
            #pragma unroll
            for (int k = 0; k <= j; ++k) sum += (double)Lf[tri(i, k)] * (double)Lf[tri(j, k)];
            if (ACCUM) dst[tri(i, j)] += sum * inv;
            else       dst[tri(i, j)]  = sum * inv;
        }
    }
}

// in-place fp64 Cholesky of sym-36 (lower). Stays fp64: chol backward error is
// absolute wrt ||A|| -> would leak absolute eigenvalue error in fp32.
__device__ __forceinline__ void chol36(double (&M)[TRIL]) {
    #pragma unroll
    for (int j = 0; j < DIM; ++j) {
        double d = M[tri(j, j)];
        #pragma unroll
        for (int k = 0; k < j; ++k) d -= M[tri(j, k)] * M[tri(j, k)];
        d = fmax(d, 1.0e-30);
        double invd = fast_rsqrt(d);
        M[tri(j, j)] = d * invd;
        #pragma unroll
        for (int i = j + 1; i < DIM; ++i) {
            double v = M[tri(i, j)];
            #pragma unroll
            for (int k = 0; k < j; ++k) v -= M[tri(i, k)] * M[tri(j, k)];
            M[tri(i, j)] = v * invd;
        }
    }
}

// 4 lanes cooperate per batch element. Lane g owns G columns (2g, 2g+1).
__global__ void __launch_bounds__(64)
qcbow_kernel(const int* __restrict__ contexts,  // [NB, SEQ]
             const int* __restrict__ targets,   // [NB]
             const float* __restrict__ emb,     // [100000, TRIL]
             float* __restrict__ out)           // [NB]
{
    const int tid = blockIdx.x * 64 + threadIdx.x;
    const int b = tid >> 2;
    const int g = threadIdx.x & 3;

    // ---- phase 1: partial context density (tokens g, g+4, g+8) ----
    double A[TRIL];
    #pragma unroll
    for (int i = 0; i < TRIL; ++i) A[i] = 0.0;
    float cntf = 0.0f;
    for (int s = g; s < SEQ; s += 4) {
        int tok = contexts[b * SEQ + s];
        if (tok != 0) {
            add_density<true>(emb + (size_t)tok * TRIL, A);
            cntf += 1.0f;
        }
    }

    // ---- sigma (target density), redundant on all 4 lanes (same cachelines) ----
    double W[TRIL];
    add_density<false>(emb + (size_t)targets[b] * TRIL, W);

    // ---- allreduce A,cnt over the quad via DPP (VALU, no DS latency) ----
    #pragma unroll
    for (int i = 0; i < TRIL; ++i) A[i] += dperm<0xB1>(A[i]);   // xor 1
    cntf += fperm<0xB1>(cntf);
    #pragma unroll
    for (int i = 0; i < TRIL; ++i) A[i] += dperm<0x4E>(A[i]);   // xor 2
    cntf += fperm<0x4E>(cntf);

    // W <- chol(sigma)
    chol36(W);

    // ---- A <- rho_ctx + 1e-6 I ; A <- Lc = chol(A) ----
    double invc = fast_rcp((double)cntf);
    #pragma unroll
    for (int i = 0; i < TRIL; ++i) A[i] *= invc;
    #pragma unroll
    for (int d = 0; d < DIM; ++d) A[tri(d, d)] += 1.0e-6;
    chol36(A);

    // ---- G = Lc^T * W in fp64; lane g takes columns (2g, 2g+1), cast to fp32.
    // eig((rho+eps I) sigma) = eig(G G^T) = sing(G)^2 = final column norms^2.
    double wa[DIM], wb[DIM];
#define PICKW(JA, JB)                                                              \
    {                                                                              \
        _Pragma("unroll")                                                          \
        for (int k = 0; k < DIM; ++k) wa[k] = (k >= (JA)) ? W[tri(k, (JA))] : 0.0; \
        _Pragma("unroll")                                                          \
        for (int k = 0; k < DIM; ++k) wb[k] = (k >= (JB)) ? W[tri(k, (JB))] : 0.0; \
    }
    switch (g) {
        case 0: PICKW(0, 1); break;
        case 1: PICKW(2, 3); break;
        case 2: PICKW(4, 5); break;
        default: PICKW(6, 7); break;
    }
#undef PICKW

    float a[DIM], bb[DIM];   // my two G columns, fp32 (rotation errors are column-relative)
    #pragma unroll
    for (int i = 0; i < DIM; ++i) {
        double sa = 0.0, sb = 0.0;
        #pragma unroll
        for (int k = i; k < DIM; ++k) {
            double lk = A[tri(k, i)];      // (Lc^T)[i][k]
            sa += lk * wa[k];
            sb += lk * wb[k];
        }
        a[i] = (float)sa; bb[i] = (float)sb;
    }

    // ---- systolic one-sided Jacobi (Brent-Luk), fp32, DPP exchange.
    // Exchange cycle covers all 28 pairs in 7 rounds (verified R3, absmax at floor).
    // Convergence: z^2 <= 1e-12*x*y (cluster-safe) OR z^2 <= 1e-12*(x-y)^2
    // (fp32-angle residual ~1e-7*|x-y|; implies dLambda <= 1e-12*|x-y| -- harmless).
    for (int sweep = 0; sweep < 8; ++sweep) {
        bool conv = true;
        #pragma unroll
        for (int r = 0; r < 7; ++r) {
            float x = 0.0f, y = 0.0f, z = 0.0f;
            #pragma unroll
            for (int k = 0; k < DIM; ++k) {
                x = fmaf(a[k], a[k], x);
                y = fmaf(bb[k], bb[k], y);
                z = fmaf(a[k], bb[k], z);
            }
            float z2 = z * z;
            float d  = x - y;
            if (z2 > 1.0e-12f * x * y && z2 > 1.0e-12f * d * d) conv = false;
            if (z2 > 1.0e-16f * x * y) {   // skip pure-noise rotations; guards rcp(0)
                float tau = -d * (0.5f * __builtin_amdgcn_rcpf(z));
                float t = __builtin_amdgcn_rcpf(fabsf(tau) + sqrtf(fmaf(tau, tau, 1.0f)));
                t = (tau >= 0.0f) ? t : -t;
                float c = __builtin_amdgcn_rsqf(fmaf(t, t, 1.0f));
                float s = t * c;
                #pragma unroll
                for (int k = 0; k < DIM; ++k) {
                    float na = c * a[k] - s * bb[k];
                    float nb = s * a[k] + c * bb[k];
                    a[k] = na; bb[k] = nb;
                }
            }
            // systolic exchange, single-cycle DPP quad perms:
            #pragma unroll
            for (int k = 0; k < DIM; ++k) {
                float olda = a[k];
                float sa = (g == 0) ? bb[k] : a[k];
                float ta = fperm<0x93>(sa);       // from lane (g+3)&3
                float tb = fperm<0x39>(bb[k]);    // from lane (g+1)&3
                a[k]  = (g == 0) ? olda : ta;
                bb[k] = (g == 3) ? olda : tb;
            }
        }
        if (sweep >= 2 && __all(conv)) break;
    }

    // ---- fidelity: lambda_i = ||col_i||^2 (fp64 norms of fp32 cols: relative-accurate) ----
    double xn = 0.0, yn = 0.0;
    #pragma unroll
    for (int k = 0; k < DIM; ++k) {
        xn += (double)a[k] * (double)a[k];
        yn += (double)bb[k] * (double)bb[k];
    }
    double fp = fast_sqrt(xn + 1.0e-6) + fast_sqrt(yn + 1.0e-6);
    fp += dperm<0xB1>(fp);
    fp += dperm<0x4E>(fp);
    if (g == 0) {
        double f = fmin(fp, 1.0);
        f = fmax(f, 1.0e-8);
        out[b] = (float)(-log(f));
    }
}

extern "C" void kernel_launch(void* const* d_in, const int* in_sizes, int n_in,
                              void* d_out, int out_size, void* d_ws, size_t ws_size,
                              hipStream_t stream) {
    const int*   contexts = (const int*)d_in[0];
    const int*   targets  = (const int*)d_in[1];
    const float* emb      = (const float*)d_in[2];
    float*       out      = (float*)d_out;

    qcbow_kernel<<<dim3(NB * 4 / 64), dim3(64), 0, stream>>>(contexts, targets, emb, out);
}